// Round 11
// baseline (196.768 us; speedup 1.0000x reference)
//
#include <hip/hip_runtime.h>
#include <cstddef>
#include <cstdint>

typedef __attribute__((ext_vector_type(8))) short bf16x8;   // 8 bf16 = 4 VGPR
typedef __attribute__((ext_vector_type(16))) float f32x16;  // MFMA 32x32 acc

static constexpr float LN2 = 0.69314718055994530942f;
static constexpr float INV_LN2 = 1.44269504088896340736f;

__device__ __forceinline__ unsigned short f2bf(float f) {
  unsigned int u = __float_as_uint(f);
  u += 0x7fffu + ((u >> 16) & 1u);   // RNE
  return (unsigned short)(u >> 16);
}

__device__ __forceinline__ unsigned int cvt_pk_bf16(float a, float b) {
  unsigned int r;
  asm("v_cvt_pk_bf16_f32 %0, %1, %2" : "=v"(r) : "v"(a), "v"(b));
  return r;
}

__device__ __forceinline__ float hw_exp2(float x) {
  float r;
  asm("v_exp_f32 %0, %1" : "=v"(r) : "v"(x));
  return r;
}
__device__ __forceinline__ float hw_log2(float x) {
  float r;
  asm("v_log_f32 %0, %1" : "=v"(r) : "v"(x));
  return r;
}

// softplus(x)-ln2 = max(x,0)-ln2 + ln2*log2(1+2^(-|x|/ln2)); rel err ~1e-5
__device__ __forceinline__ float shsp(float x) {
  float t = hw_exp2(-fabsf(x) * INV_LN2);
  float l = hw_log2(1.0f + t);
  return fmaf(LN2, l, fmaxf(x, 0.0f) - LN2);
}

// async 16B global -> LDS (lane l writes lds + l*16)
__device__ __forceinline__ void async_copy16(const void* g, void* l) {
  __builtin_amdgcn_global_load_lds(
      (const __attribute__((address_space(1))) void*)g,
      (__attribute__((address_space(3))) void*)l, 16, 0, 0);
}

#define WAITV(N) asm volatile("s_waitcnt vmcnt(" #N ")" ::: "memory")

// ---- prep: h (N*64 f32) -> bf16 ----
__global__ void prep_h_kernel(const float* __restrict__ h,
                              unsigned short* __restrict__ hbf, int n4) {
  int i = blockIdx.x * 256 + threadIdx.x;
  if (i < n4) {
    float4 v = reinterpret_cast<const float4*>(h)[i];
    uint2 o;
    o.x = cvt_pk_bf16(v.x, v.y);
    o.y = cvt_pk_bf16(v.z, v.w);
    reinterpret_cast<uint2*>(hbf)[i] = o;
  }
}

// ---- prep: pack W1^T, W2^T into MFMA-fragment order (bf16), kk-major ----
__global__ void prep_w_kernel(const float* __restrict__ W1,
                              const float* __restrict__ W2,
                              unsigned short* __restrict__ Wp1,
                              unsigned short* __restrict__ Wp2) {
  int j = blockIdx.x * 256 + threadIdx.x;
  if (j < 48 * 64) {
    int f  = j / 64;
    int l  = j % 64;
    int kk = f >> 2;
    int mt = f & 3;
    int col = mt * 32 + (l & 31);
    int kb  = kk * 16 + (l >> 5) * 8;
    #pragma unroll
    for (int i = 0; i < 8; ++i)
      Wp1[(size_t)j * 8 + i] = f2bf(W1[(size_t)(kb + i) * 128 + col]);
  } else if (j < 48 * 64 + 16 * 64) {
    int jj = j - 48 * 64;
    int f  = jj / 64;
    int l  = jj % 64;
    int kk = f >> 1;
    int mt = f & 1;
    int oc = mt * 32 + (l & 31);
    int kb = kk * 16 + (l >> 5) * 8;
    #pragma unroll
    for (int i = 0; i < 8; ++i)
      Wp2[(size_t)jj * 8 + i] = f2bf(W2[(size_t)(kb + i) * 64 + oc]);
  }
}

// ---- main fused kernel: wave-local 2-phase pipeline (T3 minimal) ----
// 256 threads (4 waves), 1 block/CU. LDS 144K = W1L 48K + 4 x 24K/wave:
//   HA double-buffer 2x8K (h bf16 -> X bf16 -> out f32 lifecycle, XOR-swz),
//   EA 4K single (ea(t) consumed by GEMM1(t) before ea(t+1) ds_write; DS
//   pipe is in-order per wave so WAR needs no wait).
// Per tile: WAITV(8) [h(t) landed: the 8 stores(t-1) are always the
//   youngest vmem, so outstanding<=8 => h(t) retired — compiler-proof],
//   issue ea(t+1)->VGPR + h(t+1)->global_load_lds[HA other buf] + idx(t+2),
//   then GEMM1/epi1/GEMM2/epi2/stores of t overlap those loads.
// No __syncthreads in the loop; h never passes through VGPRs.
__global__ __launch_bounds__(256, 1)
void edge_mlp_kernel(const float* __restrict__ ea,
                     const int* __restrict__ eidx,
                     const float* __restrict__ b1,
                     const float* __restrict__ b2,
                     const unsigned short* __restrict__ hbf,
                     const unsigned short* __restrict__ Wp1,
                     const unsigned short* __restrict__ Wp2,
                     float* __restrict__ out,
                     int E, int ntiles) {
  __shared__ __align__(16) unsigned char LDS[147456];

  const int tid  = threadIdx.x;
  const int lane = tid & 63;
  const int w    = tid >> 6;          // 0..3
  const int lo   = lane & 31;
  const int hi   = lane >> 5;
  const int rsw  = lo & 7;
  const int lr4  = lane >> 4;         // staging row-within-4
  const int p    = lane & 15;         // staging chunk position

  unsigned char* W1L = LDS;
  unsigned char* HA0 = LDS + 49152 + w * 24576;       // buffer 0 (8K)
  unsigned char* EAw = HA0 + 16384;                   // 4K

  // ---- stage W1 into LDS once (48KB = 3072 chunks of 16B) ----
  #pragma unroll
  for (int j = 0; j < 12; ++j) {
    int ch = j * 256 + w * 64;
    async_copy16(Wp1 + (size_t)(ch + lane) * 8, LDS + ch * 16);
  }
  __syncthreads();                      // once; drains vmcnt

  const int gw     = blockIdx.x * 4 + w;
  const int nwaves = gridDim.x * 4;

  float4 areg[8];
  int nodeN = 0, nodeN2 = 0;

#define LOADIDX(t) eidx[(size_t)(lane & 1) * E + (size_t)(t) * 32 + (lane >> 1)]

#define LOADEA_REG(t) { \
  _Pragma("unroll") for (int it = 0; it < 8; ++it) \
    areg[it] = *reinterpret_cast<const float4*>( \
        ea + (size_t)((t) * 32 + it * 4 + lr4) * 64 + p * 4); }

#define DSWRITE_EA() { \
  _Pragma("unroll") for (int it = 0; it < 8; ++it) { \
    int r_ = it * 4 + lr4; \
    uint2 o_; \
    o_.x = cvt_pk_bf16(areg[it].x, areg[it].y); \
    o_.y = cvt_pk_bf16(areg[it].z, areg[it].w); \
    *reinterpret_cast<uint2*>( \
        EAw + r_ * 128 + (((p >> 1) ^ (r_ & 7)) * 16) + (p & 1) * 8) = o_; \
  } }

#define ISSUE_H(NODE, HBASE) { \
  _Pragma("unroll") for (int it = 0; it < 8; ++it) { \
    int r_ = it * 4 + lr4; \
    int c_ = p ^ (r_ & 7); \
    int nd_ = __shfl(NODE, r_ * 2 + (c_ >> 3), 64); \
    async_copy16(hbf + (size_t)nd_ * 64 + (c_ & 7) * 8, (HBASE) + it * 1024); \
  } }

  // ---- prologue: fill EA(t0), issue h(t0) -> HA0, idx(t1) ----
  int t = gw;
  if (t < ntiles) {
    LOADEA_REG(t)
    DSWRITE_EA()
    int node0 = LOADIDX(t);
    ISSUE_H(node0, HA0)
    if (t + nwaves < ntiles) nodeN = LOADIDX(t + nwaves);
    WAITV(0);                           // drain once: invariant holds from here
  }

  int cur = 0;
  for (; t < ntiles; t += nwaves) {
    unsigned char* HAc = HA0 + cur * 8192;
    unsigned char* HAn = HA0 + (cur ^ 1) * 8192;
    const int eb = t * 32;
    const int tn  = t + nwaves;
    const int tnn = tn + nwaves;

    WAITV(8);                           // h(t) retired (stores(t-1) = youngest 8)

    if (tn < ntiles) {
      LOADEA_REG(tn)                    // ea(t+1) -> VGPR (transient)
      ISSUE_H(nodeN, HAn)               // h(t+1) -> other buffer, async
    }
    if (tnn < ntiles) nodeN2 = LOADIDX(tnn);

    // ---- GEMM1: x^T = W1^T(128x192) @ concat^T ----
    f32x16 acc[4];
    #pragma unroll
    for (int m = 0; m < 4; ++m) acc[m] = (f32x16)0.0f;

    #pragma unroll
    for (int kk = 0; kk < 12; ++kk) {
      bf16x8 bfr;
      if (kk < 8) {
        bfr = *reinterpret_cast<const bf16x8*>(
            HAc + lo * 256 + (((kk * 2 + hi) ^ rsw) * 16));
      } else {
        bfr = *reinterpret_cast<const bf16x8*>(
            EAw + lo * 128 + ((((kk - 8) * 2 + hi) ^ rsw) * 16));
      }
      #pragma unroll
      for (int mt = 0; mt < 4; ++mt) {
        bf16x8 afr = *reinterpret_cast<const bf16x8*>(
            W1L + (size_t)(kk * 4 + mt) * 1024 + lane * 16);
        acc[mt] = __builtin_amdgcn_mfma_f32_32x32x16_bf16(afr, bfr, acc[mt], 0, 0, 0);
      }
    }

    // ---- epilogue 1: bias + softplus -> bf16 X rows (alias HAc) ----
    #pragma unroll
    for (int c = 0; c < 16; ++c) {
      int mt = c >> 2, g = c & 3;
      int f0 = mt * 32 + g * 8 + hi * 4;
      float4 bb = *reinterpret_cast<const float4*>(b1 + f0);
      float s0 = shsp(acc[mt][g * 4 + 0] + bb.x);
      float s1 = shsp(acc[mt][g * 4 + 1] + bb.y);
      float s2 = shsp(acc[mt][g * 4 + 2] + bb.z);
      float s3 = shsp(acc[mt][g * 4 + 3] + bb.w);
      uint2 o;
      o.x = cvt_pk_bf16(s0, s1);
      o.y = cvt_pk_bf16(s2, s3);
      *reinterpret_cast<uint2*>(HAc + lo * 256 + ((c ^ rsw) * 16) + hi * 8) = o;
    }

    // ea(t+1) -> EA (after GEMM1's EA reads; DS pipe in-order per wave)
    if (tn < ntiles) { DSWRITE_EA() }

    // ---- GEMM2: out^T = W2^T(64x128) @ x (W2 frags via global/L1) ----
    f32x16 acc2[2];
    #pragma unroll
    for (int m = 0; m < 2; ++m) acc2[m] = (f32x16)0.0f;

    #pragma unroll
    for (int kk = 0; kk < 8; ++kk) {
      bf16x8 bfr = *reinterpret_cast<const bf16x8*>(
          HAc + lo * 256 + (((kk * 2 + hi) ^ rsw) * 16));
      #pragma unroll
      for (int mt = 0; mt < 2; ++mt) {
        bf16x8 afr = *reinterpret_cast<const bf16x8*>(
            Wp2 + ((size_t)(kk * 2 + mt) * 64 + lane) * 8);
        acc2[mt] = __builtin_amdgcn_mfma_f32_32x32x16_bf16(afr, bfr, acc2[mt], 0, 0, 0);
      }
    }

    // ---- epilogue 2: bias -> f32 out rows in LDS (alias HAc again) ----
    #pragma unroll
    for (int mt = 0; mt < 2; ++mt) {
      #pragma unroll
      for (int g = 0; g < 4; ++g) {
        int oc0 = mt * 32 + g * 8 + hi * 4;
        float4 bb = *reinterpret_cast<const float4*>(b2 + oc0);
        float4 o;
        o.x = acc2[mt][g * 4 + 0] + bb.x;
        o.y = acc2[mt][g * 4 + 1] + bb.y;
        o.z = acc2[mt][g * 4 + 2] + bb.z;
        o.w = acc2[mt][g * 4 + 3] + bb.w;
        int c = mt * 8 + g * 2 + hi;
        *reinterpret_cast<float4*>(HAc + lo * 256 + ((c ^ rsw) * 16)) = o;
      }
    }

    // ---- coalesced stores: exactly 8 global_store_dwordx4 (the youngest
    //      vmem of this tile — the WAITV(8) count anchor) ----
    #pragma unroll
    for (int it = 0; it < 8; ++it) {
      int r = it * 4 + lr4;
      float4 v = *reinterpret_cast<const float4*>(HAc + r * 256 + p * 16);
      int c = p ^ (r & 7);
      *reinterpret_cast<float4*>(out + (size_t)(eb + r) * 64 + c * 4) = v;
    }

    nodeN = nodeN2;
    cur ^= 1;
  }
}

extern "C" void kernel_launch(void* const* d_in, const int* in_sizes, int n_in,
                              void* d_out, int out_size, void* d_ws, size_t ws_size,
                              hipStream_t stream) {
  const float* h  = (const float*)d_in[0];
  const float* ea = (const float*)d_in[1];
  const int*  idx = (const int*)d_in[2];
  const float* W1 = (const float*)d_in[3];
  const float* b1 = (const float*)d_in[4];
  const float* W2 = (const float*)d_in[5];
  const float* b2 = (const float*)d_in[6];
  float* out = (float*)d_out;

  const int N = in_sizes[0] / 64;      // 50000
  const int E = in_sizes[1] / 64;      // 800000

  unsigned short* hbf = (unsigned short*)d_ws;                       // N*64 bf16
  size_t off1 = (size_t)N * 64 * 2;
  unsigned short* Wp1 = (unsigned short*)((char*)d_ws + off1);       // 24576 bf16
  unsigned short* Wp2 = (unsigned short*)((char*)d_ws + off1 + 24576 * 2);

  int n4 = (N * 64) / 4;
  prep_h_kernel<<<(n4 + 255) / 256, 256, 0, stream>>>(h, hbf, n4);
  prep_w_kernel<<<16, 256, 0, stream>>>(W1, W2, Wp1, Wp2);

  int ntiles = E / 32;                  // 25000 wave-tiles
  edge_mlp_kernel<<<256, 256, 0, stream>>>(ea, idx, b1, b2, hbf, Wp1, Wp2,
                                           out, E, ntiles);
}

// Round 12
// 144.885 us; speedup vs baseline: 1.3581x; 1.3581x over previous
//
#include <hip/hip_runtime.h>
#include <cstddef>
#include <cstdint>

typedef __attribute__((ext_vector_type(8))) short bf16x8;   // 8 bf16 = 4 VGPR
typedef __attribute__((ext_vector_type(16))) float f32x16;  // MFMA 32x32 acc

static constexpr float LN2 = 0.69314718055994530942f;
static constexpr float INV_LN2 = 1.44269504088896340736f;

__device__ __forceinline__ unsigned short f2bf(float f) {
  unsigned int u = __float_as_uint(f);
  u += 0x7fffu + ((u >> 16) & 1u);   // RNE
  return (unsigned short)(u >> 16);
}

__device__ __forceinline__ unsigned int cvt_pk_bf16(float a, float b) {
  unsigned int r;
  asm("v_cvt_pk_bf16_f32 %0, %1, %2" : "=v"(r) : "v"(a), "v"(b));
  return r;
}

__device__ __forceinline__ float hw_exp2(float x) {
  float r;
  asm("v_exp_f32 %0, %1" : "=v"(r) : "v"(x));
  return r;
}
__device__ __forceinline__ float hw_log2(float x) {
  float r;
  asm("v_log_f32 %0, %1" : "=v"(r) : "v"(x));
  return r;
}

// softplus(x)-ln2 = max(x,0)-ln2 + ln2*log2(1+2^(-|x|/ln2)); rel err ~1e-5
__device__ __forceinline__ float shsp(float x) {
  float t = hw_exp2(-fabsf(x) * INV_LN2);
  float l = hw_log2(1.0f + t);
  return fmaf(LN2, l, fmaxf(x, 0.0f) - LN2);
}

// async 16B global -> LDS (lane l writes lds + l*16)
__device__ __forceinline__ void async_copy16(const void* g, void* l) {
  __builtin_amdgcn_global_load_lds(
      (const __attribute__((address_space(1))) void*)g,
      (__attribute__((address_space(3))) void*)l, 16, 0, 0);
}

#define WAITV(N) asm volatile("s_waitcnt vmcnt(" #N ")" ::: "memory")

// ---- prep: h (N*64 f32) -> bf16 ----
__global__ void prep_h_kernel(const float* __restrict__ h,
                              unsigned short* __restrict__ hbf, int n4) {
  int i = blockIdx.x * 256 + threadIdx.x;
  if (i < n4) {
    float4 v = reinterpret_cast<const float4*>(h)[i];
    uint2 o;
    o.x = cvt_pk_bf16(v.x, v.y);
    o.y = cvt_pk_bf16(v.z, v.w);
    reinterpret_cast<uint2*>(hbf)[i] = o;
  }
}

// ---- prep: pack W1^T, W2^T into MFMA-fragment order (bf16), kk-major ----
__global__ void prep_w_kernel(const float* __restrict__ W1,
                              const float* __restrict__ W2,
                              unsigned short* __restrict__ Wp1,
                              unsigned short* __restrict__ Wp2) {
  int j = blockIdx.x * 256 + threadIdx.x;
  if (j < 48 * 64) {
    int f  = j / 64;
    int l  = j % 64;
    int kk = f >> 2;
    int mt = f & 3;
    int col = mt * 32 + (l & 31);
    int kb  = kk * 16 + (l >> 5) * 8;
    #pragma unroll
    for (int i = 0; i < 8; ++i)
      Wp1[(size_t)j * 8 + i] = f2bf(W1[(size_t)(kb + i) * 128 + col]);
  } else if (j < 48 * 64 + 16 * 64) {
    int jj = j - 48 * 64;
    int f  = jj / 64;
    int l  = jj % 64;
    int kk = f >> 1;
    int mt = f & 1;
    int oc = mt * 32 + (l & 31);
    int kb = kk * 16 + (l >> 5) * 8;
    #pragma unroll
    for (int i = 0; i < 8; ++i)
      Wp2[(size_t)jj * 8 + i] = f2bf(W2[(size_t)(kb + i) * 64 + oc]);
  }
}

// ---- main fused kernel: 2-phase pipelined waves x 7 (R11 schedule, lean LDS) ----
// 448 threads (7 waves), 1 block/CU. LDS 160K = W1L 48K + 7 x 16K h-dbuf.
//   ea: per-lane VGPRs (R6-verified frag mapping, cvt_pk at use).
//   X: never touches LDS — in-register __shfl_xor(32) half-exchange
//      (R6-verified) feeds GEMM2 B-frags directly.
//   out: f32 tile written into the CURRENT h buffer (dead after GEMM1),
//      then read back permuted for 1KB-coalesced stores.
// Per tile: WAITV(8) [stores(t-1) are always the youngest 8 vmem ops ->
//   h(t) retired], issue h(t+1) async + idx(t+2); GEMM1; issue ea(t+1);
//   epi1 -> shfl exchange -> GEMM2 -> out. No barriers in the loop.
__global__ __launch_bounds__(448, 1)
void edge_mlp_kernel(const float* __restrict__ ea,
                     const int* __restrict__ eidx,
                     const float* __restrict__ b1,
                     const float* __restrict__ b2,
                     const unsigned short* __restrict__ hbf,
                     const unsigned short* __restrict__ Wp1,
                     const unsigned short* __restrict__ Wp2,
                     float* __restrict__ out,
                     int E, int ntiles) {
  __shared__ __align__(16) unsigned char LDS[163840];

  const int tid  = threadIdx.x;
  const int lane = tid & 63;
  const int w    = tid >> 6;          // 0..6
  const int lo   = lane & 31;
  const int hi   = lane >> 5;
  const int rsw  = lo & 7;
  const int lr4  = lane >> 4;         // staging row-within-4
  const int p    = lane & 15;         // staging chunk position

  unsigned char* W1L = LDS;
  unsigned char* HA0 = LDS + 49152 + w * 16384;   // 2 x 8K dbuf

  // ---- stage W1 into LDS once (48KB = 48 groups of 64 chunks) ----
  #pragma unroll
  for (int j = 0; j < 7; ++j) {
    int grp = j * 7 + w;               // base-7: each group 0..48 hit once
    if (grp < 48) {
      int ch = grp * 64;
      async_copy16(Wp1 + (size_t)(ch + lane) * 8, LDS + ch * 16);
    }
  }
  __syncthreads();                      // once; drains vmcnt

  const int gw     = blockIdx.x * 7 + w;
  const int nwaves = gridDim.x * 7;

  float4 eareg[8];
  int nodeN = 0, nodeN2 = 0;

#define LOADIDX(t) eidx[(size_t)(lane & 1) * E + (size_t)(t) * 32 + (lane >> 1)]

// per-lane ea: lane (lo,hi) holds row eb+lo, chunks hi*8.. (R6 mapping)
#define LOADEA(t) { \
  const float* eab_ = ea + (size_t)((t) * 32 + lo) * 64; \
  _Pragma("unroll") for (int j = 0; j < 4; ++j) { \
    eareg[2 * j]     = *reinterpret_cast<const float4*>(eab_ + j * 16 + hi * 8); \
    eareg[2 * j + 1] = *reinterpret_cast<const float4*>(eab_ + j * 16 + hi * 8 + 4); \
  } }

#define ISSUE_H(NODE, HBASE) { \
  _Pragma("unroll") for (int it = 0; it < 8; ++it) { \
    int r_ = it * 4 + lr4; \
    int c_ = p ^ (r_ & 7); \
    int nd_ = __shfl(NODE, r_ * 2 + (c_ >> 3), 64); \
    async_copy16(hbf + (size_t)nd_ * 64 + (c_ & 7) * 8, (HBASE) + it * 1024); \
  } }

  // ---- prologue ----
  int t = gw;
  if (t < ntiles) {
    LOADEA(t)
    int node0 = LOADIDX(t);
    ISSUE_H(node0, HA0)
    if (t + nwaves < ntiles) nodeN = LOADIDX(t + nwaves);
    WAITV(0);
  }

  int cur = 0;
  for (; t < ntiles; t += nwaves) {
    unsigned char* HAc = HA0 + cur * 8192;
    unsigned char* HAn = HA0 + (cur ^ 1) * 8192;
    const int eb  = t * 32;
    const int tn  = t + nwaves;
    const int tnn = tn + nwaves;

    WAITV(8);                           // h(t) retired (stores(t-1) youngest)

    if (tn < ntiles)  { ISSUE_H(nodeN, HAn) }    // h(t+1) async
    if (tnn < ntiles) { nodeN2 = LOADIDX(tnn); }

    // ---- GEMM1: x^T = W1^T(128x192) @ concat^T ----
    f32x16 acc[4];
    #pragma unroll
    for (int m = 0; m < 4; ++m) acc[m] = (f32x16)0.0f;

    #pragma unroll
    for (int kk = 0; kk < 12; ++kk) {
      bf16x8 bfr;
      if (kk < 8) {
        bfr = *reinterpret_cast<const bf16x8*>(
            HAc + lo * 256 + (((kk * 2 + hi) ^ rsw) * 16));
      } else {
        float4 lo4 = eareg[(kk - 8) * 2];
        float4 hi4 = eareg[(kk - 8) * 2 + 1];
        union { bf16x8 v; unsigned u[4]; } tt;
        tt.u[0] = cvt_pk_bf16(lo4.x, lo4.y);
        tt.u[1] = cvt_pk_bf16(lo4.z, lo4.w);
        tt.u[2] = cvt_pk_bf16(hi4.x, hi4.y);
        tt.u[3] = cvt_pk_bf16(hi4.z, hi4.w);
        bfr = tt.v;
      }
      #pragma unroll
      for (int mt = 0; mt < 4; ++mt) {
        bf16x8 afr = *reinterpret_cast<const bf16x8*>(
            W1L + (size_t)(kk * 4 + mt) * 1024 + lane * 16);
        acc[mt] = __builtin_amdgcn_mfma_f32_32x32x16_bf16(afr, bfr, acc[mt], 0, 0, 0);
      }
    }

    // ea(t+1) -> VGPRs (overlaps epi/GEMM2/stores; eareg free after GEMM1)
    if (tn < ntiles) { LOADEA(tn) }

    // ---- epilogue 1: bias + softplus, packed bf16 in-register ----
    unsigned u0[16], u1[16];
    #pragma unroll
    for (int c = 0; c < 16; ++c) {
      int mt = c >> 2, g = c & 3;
      int f0 = mt * 32 + g * 8 + hi * 4;
      float4 bb = *reinterpret_cast<const float4*>(b1 + f0);
      float s0 = shsp(acc[mt][g * 4 + 0] + bb.x);
      float s1 = shsp(acc[mt][g * 4 + 1] + bb.y);
      float s2 = shsp(acc[mt][g * 4 + 2] + bb.z);
      float s3 = shsp(acc[mt][g * 4 + 3] + bb.w);
      u0[c] = cvt_pk_bf16(s0, s1);
      u1[c] = cvt_pk_bf16(s2, s3);
    }

    // ---- half-exchange lane <-> lane^32 (R6-verified) -> GEMM2 B-frags ----
    unsigned pa[8][4];
    #pragma unroll
    for (int kk = 0; kk < 8; ++kk) {
      unsigned x0 = u0[2 * kk], y0 = u0[2 * kk + 1];
      unsigned x1 = u1[2 * kk], y1 = u1[2 * kk + 1];
      unsigned s0 = hi ? x0 : y0;
      unsigned s1 = hi ? x1 : y1;
      unsigned t0 = (unsigned)__shfl_xor((int)s0, 32, 64);
      unsigned t1 = (unsigned)__shfl_xor((int)s1, 32, 64);
      pa[kk][0] = hi ? t0 : x0;
      pa[kk][1] = hi ? t1 : x1;
      pa[kk][2] = hi ? y0 : t0;
      pa[kk][3] = hi ? y1 : t1;
    }

    // ---- GEMM2: out^T = W2^T(64x128) @ x (W2 frags via global/L1) ----
    f32x16 acc2[2];
    #pragma unroll
    for (int m = 0; m < 2; ++m) acc2[m] = (f32x16)0.0f;

    #pragma unroll
    for (int kk = 0; kk < 8; ++kk) {
      union { bf16x8 v; unsigned u[4]; } tt;
      tt.u[0] = pa[kk][0];
      tt.u[1] = pa[kk][1];
      tt.u[2] = pa[kk][2];
      tt.u[3] = pa[kk][3];
      #pragma unroll
      for (int mt = 0; mt < 2; ++mt) {
        bf16x8 afr = *reinterpret_cast<const bf16x8*>(
            Wp2 + ((size_t)(kk * 2 + mt) * 64 + lane) * 8);
        acc2[mt] = __builtin_amdgcn_mfma_f32_32x32x16_bf16(afr, tt.v, acc2[mt], 0, 0, 0);
      }
    }

    // ---- epilogue 2: bias -> f32 out rows into HAc (h dead after GEMM1) ----
    #pragma unroll
    for (int mt = 0; mt < 2; ++mt) {
      #pragma unroll
      for (int g = 0; g < 4; ++g) {
        int oc0 = mt * 32 + g * 8 + hi * 4;
        float4 bb = *reinterpret_cast<const float4*>(b2 + oc0);
        float4 o;
        o.x = acc2[mt][g * 4 + 0] + bb.x;
        o.y = acc2[mt][g * 4 + 1] + bb.y;
        o.z = acc2[mt][g * 4 + 2] + bb.z;
        o.w = acc2[mt][g * 4 + 3] + bb.w;
        int c = mt * 8 + g * 2 + hi;          // 16B f32 chunk index
        *reinterpret_cast<float4*>(HAc + lo * 256 + ((c ^ rsw) * 16)) = o;
      }
    }

    // ---- coalesced stores: exactly 8 global_store_dwordx4 (WAITV anchor) ----
    #pragma unroll
    for (int it = 0; it < 8; ++it) {
      int r = it * 4 + lr4;
      float4 v = *reinterpret_cast<const float4*>(HAc + r * 256 + p * 16);
      int c = p ^ (r & 7);
      *reinterpret_cast<float4*>(out + (size_t)(eb + r) * 64 + c * 4) = v;
    }

    nodeN = nodeN2;
    cur ^= 1;
  }
}

extern "C" void kernel_launch(void* const* d_in, const int* in_sizes, int n_in,
                              void* d_out, int out_size, void* d_ws, size_t ws_size,
                              hipStream_t stream) {
  const float* h  = (const float*)d_in[0];
  const float* ea = (const float*)d_in[1];
  const int*  idx = (const int*)d_in[2];
  const float* W1 = (const float*)d_in[3];
  const float* b1 = (const float*)d_in[4];
  const float* W2 = (const float*)d_in[5];
  const float* b2 = (const float*)d_in[6];
  float* out = (float*)d_out;

  const int N = in_sizes[0] / 64;      // 50000
  const int E = in_sizes[1] / 64;      // 800000

  unsigned short* hbf = (unsigned short*)d_ws;                       // N*64 bf16
  size_t off1 = (size_t)N * 64 * 2;
  unsigned short* Wp1 = (unsigned short*)((char*)d_ws + off1);       // 24576 bf16
  unsigned short* Wp2 = (unsigned short*)((char*)d_ws + off1 + 24576 * 2);

  int n4 = (N * 64) / 4;
  prep_h_kernel<<<(n4 + 255) / 256, 256, 0, stream>>>(h, hbf, n4);
  prep_w_kernel<<<16, 256, 0, stream>>>(W1, W2, Wp1, Wp2);

  int ntiles = E / 32;                  // 25000 wave-tiles
  edge_mlp_kernel<<<256, 448, 0, stream>>>(ea, idx, b1, b2, hbf, Wp1, Wp2,
                                           out, E, ntiles);
}